// Round 13
// baseline (450.436 us; speedup 1.0000x reference)
//
#include <hip/hip_runtime.h>

#define NN 100000
#define NE 1600000
#define NO16 (NE / 16)                           // 100000 edges per sixteenth
#define SCAN_B 1024
#define NBLK_SCAN ((NN + SCAN_B - 1) / SCAN_B)   // 98

__device__ __forceinline__ float wave_red(float v) {
#pragma unroll
    for (int off = 32; off > 0; off >>= 1) v += __shfl_down(v, off, 64);
    return v;
}

// ---------------- build phase (once per call) --------------------------------
__global__ __launch_bounds__(256) void build1_kernel(
    const int* __restrict__ ei, int* __restrict__ cnt, int* __restrict__ posArr)
{
    int e = blockIdx.x * 256 + threadIdx.x;
    if (e < NE) posArr[e] = atomicAdd(&cnt[ei[e]], 1);
}

__global__ __launch_bounds__(SCAN_B) void scan1_kernel(
    const int* __restrict__ cnt, int* __restrict__ bsum)
{
    int i = blockIdx.x * SCAN_B + threadIdx.x;
    int v = (i < NN) ? cnt[i] : 0;
#pragma unroll
    for (int off = 32; off > 0; off >>= 1) v += __shfl_down(v, off, 64);
    __shared__ int wsum[16];
    int wave = threadIdx.x >> 6, lane = threadIdx.x & 63;
    if (lane == 0) wsum[wave] = v;
    __syncthreads();
    if (threadIdx.x == 0) {
        int s = 0;
#pragma unroll
        for (int w = 0; w < 16; w++) s += wsum[w];
        bsum[blockIdx.x] = s;
    }
}

// scan3 with scan2 folded in: each block derives its own prefix from bsum.
// off aliases cnt (block reads its cnt range before overwriting with off).
__global__ __launch_bounds__(SCAN_B) void scan3_kernel(
    const int* cnt, const int* __restrict__ bsum, int* off)
{
    __shared__ int sarr[NBLK_SCAN];
    __shared__ int sbase;
    int t = threadIdx.x;
    if (t < NBLK_SCAN) sarr[t] = bsum[t];
    __syncthreads();
    if (t == 0) {
        int s = 0;
        for (int b = 0; b < (int)blockIdx.x; b++) s += sarr[b];
        sbase = s;
    }

    __shared__ int buf[2][SCAN_B];
    int i = blockIdx.x * SCAN_B + t;
    int v = (i < NN) ? cnt[i] : 0;
    buf[0][t] = v;
    __syncthreads();
    int src = 0;
    for (int d = 1; d < SCAN_B; d <<= 1) {
        int nv = buf[src][t] + ((t >= d) ? buf[src][t - d] : 0);
        buf[src ^ 1][t] = nv;
        src ^= 1;
        __syncthreads();
    }
    if (i < NN) off[i] = sbase + buf[src][t] - v;   // exclusive
    if (blockIdx.x == NBLK_SCAN - 1 && t == SCAN_B - 1)
        off[NN] = sbase + buf[src][t];              // total = NE
}

// row-sorted records {row, col, ea0, ea1}: ONE 16B scatter per edge
__global__ __launch_bounds__(256) void fill2_kernel(
    const int* __restrict__ ei, const int* __restrict__ posArr,
    const int* __restrict__ off, const float* __restrict__ eattr,
    float4* __restrict__ rec)
{
    int e = blockIdx.x * 256 + threadIdx.x;
    if (e < NE) {
        int row = ei[e];
        int j = off[row] + posArr[e];
        float2 ea = reinterpret_cast<const float2*>(eattr)[e];
        float4 v;
        v.x = __int_as_float(row);
        v.y = __int_as_float(ei[NE + e]);
        v.z = ea.x; v.w = ea.y;
        rec[j] = v;
    }
}

// ---- P precompute for layer 0: Pr[i]=x[i]@W1[1:9], Pc[i]=x[i]@W1[9:17] ------
__global__ __launch_bounds__(256) void prep_kernel(
    const float* __restrict__ x, const float* __restrict__ W1,
    float* __restrict__ Pr, float* __restrict__ Pc)
{
    int i = blockIdx.x * 256 + threadIdx.x;
    if (i >= NN) return;
    const float4* xi = reinterpret_cast<const float4*>(x + (size_t)i * 8);
    float4 a0 = xi[0], a1 = xi[1];
    float xv[8] = {a0.x, a0.y, a0.z, a0.w, a1.x, a1.y, a1.z, a1.w};
    float pr[16], pc[16];
#pragma unroll
    for (int q = 0; q < 16; q++) { pr[q] = 0.f; pc[q] = 0.f; }
#pragma unroll
    for (int k = 0; k < 8; k++) {
        float v = xv[k];
#pragma unroll
        for (int q = 0; q < 16; q++) {
            pr[q] += v * W1[(1 + k) * 16 + q];
            pc[q] += v * W1[(9 + k) * 16 + q];
        }
    }
    float4* po = reinterpret_cast<float4*>(Pr + (size_t)i * 16);
#pragma unroll
    for (int t = 0; t < 4; t++)
        po[t] = make_float4(pr[4 * t], pr[4 * t + 1], pr[4 * t + 2], pr[4 * t + 3]);
    float4* qo = reinterpret_cast<float4*>(Pc + (size_t)i * 16);
#pragma unroll
    for (int t = 0; t < 4; t++)
        qo[t] = make_float4(pc[4 * t], pc[4 * t + 1], pc[4 * t + 2], pc[4 * t + 3]);
}

// ---------------- edge block: refactored MLP, 16 edges/thread ----------------
// h = (B1 + g*W1[0]) + Pr[row] + Pc[col] + ea0*W1[17] + ea1*W1[18]
// launch_bounds(256,2): 256-VGPR budget so the 16 rec loads + Pc gathers can
// be software-pipelined instead of serialized (r8 lesson).
template <bool EIN_FROM_REC, bool WRITE_REC, bool NEED_SUM>
__global__ __launch_bounds__(256, 2) void edge_kernel(
    float4* __restrict__ rec,
    const float* __restrict__ Pr, const float* __restrict__ Pc,
    const float* __restrict__ ein, const float* __restrict__ gptr,
    const float* __restrict__ W1, const float* __restrict__ B1,
    const float* __restrict__ W2, const float* __restrict__ B2,
    float* __restrict__ eout, float* __restrict__ esum)
{
    int j = blockIdx.x * 256 + threadIdx.x;
    float t0 = 0.f, t1 = 0.f;

    if (j < NO16) {
        float gval = gptr[0];
        float gterm[16];
#pragma unroll
        for (int q = 0; q < 16; q++) gterm[q] = B1[q] + gval * W1[q];

#pragma unroll
        for (int e = 0; e < 16; e++) {
            int jj = j + e * NO16;
            float4 r = rec[jj];
            int row = __float_as_int(r.x);
            int col = __float_as_int(r.y);
            float ea0, ea1;
            if (EIN_FROM_REC) { ea0 = r.z; ea1 = r.w; }
            else {
                float2 ea = reinterpret_cast<const float2*>(ein)[jj];
                ea0 = ea.x; ea1 = ea.y;
            }
            const float4* pr = reinterpret_cast<const float4*>(Pr + (size_t)row * 16);
            const float4* pc = reinterpret_cast<const float4*>(Pc + (size_t)col * 16);
            float4 r0 = pr[0], r1 = pr[1], r2 = pr[2], r3 = pr[3];
            float4 c0 = pc[0], c1 = pc[1], c2 = pc[2], c3 = pc[3];
            float h[16];
            h[0]  = gterm[0]  + r0.x + c0.x;
            h[1]  = gterm[1]  + r0.y + c0.y;
            h[2]  = gterm[2]  + r0.z + c0.z;
            h[3]  = gterm[3]  + r0.w + c0.w;
            h[4]  = gterm[4]  + r1.x + c1.x;
            h[5]  = gterm[5]  + r1.y + c1.y;
            h[6]  = gterm[6]  + r1.z + c1.z;
            h[7]  = gterm[7]  + r1.w + c1.w;
            h[8]  = gterm[8]  + r2.x + c2.x;
            h[9]  = gterm[9]  + r2.y + c2.y;
            h[10] = gterm[10] + r2.z + c2.z;
            h[11] = gterm[11] + r2.w + c2.w;
            h[12] = gterm[12] + r3.x + c3.x;
            h[13] = gterm[13] + r3.y + c3.y;
            h[14] = gterm[14] + r3.z + c3.z;
            h[15] = gterm[15] + r3.w + c3.w;
#pragma unroll
            for (int q = 0; q < 16; q++) {
                h[q] += ea0 * W1[17 * 16 + q];
                h[q] += ea1 * W1[18 * 16 + q];
            }
            float s0 = B2[0], s1 = B2[1];
#pragma unroll
            for (int q = 0; q < 16; q++) {
                float rr = fmaxf(h[q], 0.f);
                s0 += rr * W2[2 * q];
                s1 += rr * W2[2 * q + 1];
            }
            if (WRITE_REC) {
                float4 w;
                w.x = r.x; w.y = r.y; w.z = s0; w.w = s1;
                rec[jj] = w;
            } else {
                reinterpret_cast<float2*>(eout)[jj] = make_float2(s0, s1);
            }
            t0 += s0; t1 += s1;
        }
    }

    if (NEED_SUM) {
        float r0 = wave_red(t0);
        float r1 = wave_red(t1);
        __shared__ float red[4][2];
        int wave = threadIdx.x >> 6, lane = threadIdx.x & 63;
        if (lane == 0) { red[wave][0] = r0; red[wave][1] = r1; }
        __syncthreads();
        if (threadIdx.x == 0) {
            atomicAdd(&esum[0], red[0][0] + red[1][0] + red[2][0] + red[3][0]);
            atomicAdd(&esum[1], red[0][1] + red[1][1] + red[2][1] + red[3][1]);
        }
    }
}

// -------- node block: aggregate + MLP(11->16->8), fused next-layer P ---------
template <bool EOUT_FROM_REC, bool NEED_SUM, bool HAS_NEXT>
__global__ __launch_bounds__(256) void node_kernel(
    const float* __restrict__ x, const float* __restrict__ eout,
    const float4* __restrict__ rec,
    const int* __restrict__ off, const float* __restrict__ gptr,
    const float* __restrict__ W1, const float* __restrict__ B1,
    const float* __restrict__ W2, const float* __restrict__ B2,
    const float* __restrict__ nextW1,
    float* __restrict__ Pr, float* __restrict__ Pc,
    float* __restrict__ xout, float* __restrict__ nsum)
{
    int i = blockIdx.x * 256 + threadIdx.x;
    float out[8];
#pragma unroll
    for (int m = 0; m < 8; m++) out[m] = 0.f;

    if (i < NN) {
        float in[11];
        in[0] = gptr[0];
        const float4* xi = reinterpret_cast<const float4*>(x + (size_t)i * 8);
        float4 a0 = xi[0], a1 = xi[1];
        in[1] = a0.x; in[2] = a0.y; in[3] = a0.z; in[4] = a0.w;
        in[5] = a1.x; in[6] = a1.y; in[7] = a1.z; in[8] = a1.w;

        int b0 = off[i], b1 = off[i + 1];
        float s0 = 0.f, s1 = 0.f;
        if (EOUT_FROM_REC) {
            for (int j = b0; j < b1; j++) {
                float4 v = rec[j];
                s0 += v.z; s1 += v.w;
            }
        } else {
            const float2* e2 = reinterpret_cast<const float2*>(eout);
            const float4* e4 = reinterpret_cast<const float4*>(eout);
            int j = b0;
            if ((j & 1) && j < b1) { float2 v = e2[j]; s0 += v.x; s1 += v.y; j++; }
            for (; j + 2 <= b1; j += 2) {
                float4 v = e4[j >> 1];
                s0 += v.x + v.z; s1 += v.y + v.w;
            }
            if (j < b1) { float2 v = e2[j]; s0 += v.x; s1 += v.y; }
        }
        in[9] = s0; in[10] = s1;

        float h[16];
#pragma unroll
        for (int q = 0; q < 16; q++) h[q] = B1[q];
#pragma unroll
        for (int k = 0; k < 11; k++) {
            float v = in[k];
#pragma unroll
            for (int q = 0; q < 16; q++) h[q] += v * W1[k * 16 + q];
        }
#pragma unroll
        for (int m = 0; m < 8; m++) out[m] = B2[m];
#pragma unroll
        for (int q = 0; q < 16; q++) {
            float hq = fmaxf(h[q], 0.f);
#pragma unroll
            for (int m = 0; m < 8; m++) out[m] += hq * W2[q * 8 + m];
        }
        float4* xo = reinterpret_cast<float4*>(xout + (size_t)i * 8);
        xo[0] = make_float4(out[0], out[1], out[2], out[3]);
        xo[1] = make_float4(out[4], out[5], out[6], out[7]);

        if (HAS_NEXT) {
            float pr[16], pc[16];
#pragma unroll
            for (int q = 0; q < 16; q++) { pr[q] = 0.f; pc[q] = 0.f; }
#pragma unroll
            for (int k = 0; k < 8; k++) {
                float v = out[k];
#pragma unroll
                for (int q = 0; q < 16; q++) {
                    pr[q] += v * nextW1[(1 + k) * 16 + q];
                    pc[q] += v * nextW1[(9 + k) * 16 + q];
                }
            }
            float4* po = reinterpret_cast<float4*>(Pr + (size_t)i * 16);
#pragma unroll
            for (int t = 0; t < 4; t++)
                po[t] = make_float4(pr[4*t], pr[4*t+1], pr[4*t+2], pr[4*t+3]);
            float4* qo = reinterpret_cast<float4*>(Pc + (size_t)i * 16);
#pragma unroll
            for (int t = 0; t < 4; t++)
                qo[t] = make_float4(pc[4*t], pc[4*t+1], pc[4*t+2], pc[4*t+3]);
        }
    }
    if (NEED_SUM) {
        float r[8];
#pragma unroll
        for (int m = 0; m < 8; m++) r[m] = wave_red(out[m]);
        __shared__ float red[4][8];
        int wave = threadIdx.x >> 6, lane = threadIdx.x & 63;
        if (lane == 0) {
#pragma unroll
            for (int m = 0; m < 8; m++) red[wave][m] = r[m];
        }
        __syncthreads();
        if (threadIdx.x == 0) {
#pragma unroll
            for (int m = 0; m < 8; m++) {
                float s = red[0][m] + red[1][m] + red[2][m] + red[3][m];
                atomicAdd(&nsum[m], s);
            }
        }
    }
}

// ---------------- global block: MLP(11->16->1), single thread ----------------
__global__ void glob_kernel(const float* __restrict__ esum, const float* __restrict__ nsum,
                            const float* __restrict__ gold,
                            const float* __restrict__ W1, const float* __restrict__ B1,
                            const float* __restrict__ W2, const float* __restrict__ B2,
                            float* __restrict__ gnew)
{
    if (threadIdx.x == 0 && blockIdx.x == 0) {
        float in[11];
#pragma unroll
        for (int j = 0; j < 8; j++) in[j] = nsum[j] * (1.0f / NN);
        in[8] = esum[0] * (1.0f / NE);
        in[9] = esum[1] * (1.0f / NE);
        in[10] = gold[0];
        float acc = B2[0];
#pragma unroll
        for (int j = 0; j < 16; j++) {
            float h = B1[j];
#pragma unroll
            for (int k = 0; k < 11; k++) h += in[k] * W1[k * 16 + j];
            acc += fmaxf(h, 0.f) * W2[j];
        }
        gnew[0] = acc;
    }
}

extern "C" void kernel_launch(void* const* d_in, const int* in_sizes, int n_in,
                              void* d_out, int out_size, void* d_ws, size_t ws_size,
                              hipStream_t stream) {
    const float* x     = (const float*)d_in[0];
    const int*   ei    = (const int*)d_in[1];
    const float* eattr = (const float*)d_in[2];
    const float* g     = (const float*)d_in[3];
    const float* eW1 = (const float*)d_in[4];
    const float* eB1 = (const float*)d_in[5];
    const float* eW2 = (const float*)d_in[6];
    const float* eB2 = (const float*)d_in[7];
    const float* nW1 = (const float*)d_in[8];
    const float* nB1 = (const float*)d_in[9];
    const float* nW2 = (const float*)d_in[10];
    const float* nB2 = (const float*)d_in[11];
    const float* gW1 = (const float*)d_in[12];
    const float* gB1 = (const float*)d_in[13];
    const float* gW2 = (const float*)d_in[14];
    const float* gB2 = (const float*)d_in[15];
    float* out = (float*)d_out;

    char* ws = (char*)d_ws;
    float*  xb0    = (float*)(ws);                 // 3,200,000
    int*    off    = (int*)  (ws + 3200000);       // 400,004 (aliases cnt)
    int*    cnt    = off;
    int*    bsum   = (int*)  (ws + 3600064);       // 392
    float*  esum   = (float*)(ws + 3601024);       // 2
    float*  nsum   = (float*)(ws + 3601056);       // 8
    float*  g1     = (float*)(ws + 3601088);
    float*  g2     = g1 + 1;
    float*  eb0    = (float*)(ws + 3601152);       // 12,800,000
    float4* rec    = (float4*)(ws + 16401152);     // 25,600,000
    float*  Pr     = (float*)(ws + 42001152);      // 6,400,000 (aliases posArr)
    int*    posArr = (int*)  Pr;
    float*  Pc     = (float*)(ws + 48401152);      // 6,400,000 -> ends 54,801,152
    float*  xb1    = out;                          // d_out doubles as x buffer

    dim3 blk(256);
    dim3 egrid(NE / 256);                          // 6250 (build/fill)
    dim3 e16grid((NO16 + 255) / 256);              // 391 (edge MLP, 16 edges/thread)
    dim3 ngrid((NN + 255) / 256);                  // 391

    // ---- build row-sorted packed records (once per call) ----
    hipMemsetAsync(cnt, 0, 400000, stream);
    hipMemsetAsync(esum, 0, 64, stream);
    build1_kernel<<<egrid, blk, 0, stream>>>(ei, cnt, posArr);
    scan1_kernel<<<NBLK_SCAN, SCAN_B, 0, stream>>>(cnt, bsum);
    scan3_kernel<<<NBLK_SCAN, SCAN_B, 0, stream>>>(cnt, bsum, off);
    fill2_kernel<<<egrid, blk, 0, stream>>>(ei, posArr, off, eattr, rec);
    prep_kernel<<<ngrid, blk, 0, stream>>>(x, eW1, Pr, Pc);   // posArr dead now

    // ---- layer 0: ein = rec.zw -> eout eb0; node fuses P for L1 ----
    edge_kernel<true, false, true><<<e16grid, blk, 0, stream>>>(rec, Pr, Pc,
        nullptr, g, eW1, eB1, eW2, eB2, eb0, esum);
    node_kernel<false, true, true><<<ngrid, blk, 0, stream>>>(x, eb0, rec, off, g,
        nW1, nB1, nW2, nB2, eW1 + 304, Pr, Pc, xb0, nsum);
    glob_kernel<<<1, 64, 0, stream>>>(esum, nsum, g, gW1, gB1, gW2, gB2, g1);

    // ---- layer 1: ein = eb0 -> eout rec.zw (full 16B rewrite); node reads rec
    hipMemsetAsync(esum, 0, 64, stream);
    edge_kernel<false, true, true><<<e16grid, blk, 0, stream>>>(rec, Pr, Pc,
        eb0, g1, eW1 + 304, eB1 + 16, eW2 + 32, eB2 + 2, nullptr, esum);
    node_kernel<true, true, true><<<ngrid, blk, 0, stream>>>(xb0, nullptr, rec, off, g1,
        nW1 + 176, nB1 + 16, nW2 + 128, nB2 + 8, eW1 + 608, Pr, Pc, xb1, nsum);
    glob_kernel<<<1, 64, 0, stream>>>(esum, nsum, g1, gW1 + 176, gB1 + 16, gW2 + 16, gB2 + 1, g2);

    // ---- layer 2: ein = rec.zw -> eout eb0; node output -> d_out ----
    edge_kernel<true, false, false><<<e16grid, blk, 0, stream>>>(rec, Pr, Pc,
        nullptr, g2, eW1 + 608, eB1 + 32, eW2 + 64, eB2 + 4, eb0, esum);
    node_kernel<false, false, false><<<ngrid, blk, 0, stream>>>(xb1, eb0, rec, off, g2,
        nW1 + 352, nB1 + 32, nW2 + 256, nB2 + 16, nullptr, nullptr, nullptr, out, nsum);
}

// Round 14
// 399.604 us; speedup vs baseline: 1.1272x; 1.1272x over previous
//
#include <hip/hip_runtime.h>

#define NN 100000
#define NE 1600000
#define SCAN_B 1024
#define NBLK_SCAN ((NN + SCAN_B - 1) / SCAN_B)   // 98

__device__ __forceinline__ float wave_red(float v) {
#pragma unroll
    for (int off = 32; off > 0; off >>= 1) v += __shfl_down(v, off, 64);
    return v;
}

// ---------------- build phase (once per call) --------------------------------
__global__ __launch_bounds__(256) void build1_kernel(
    const int* __restrict__ ei, int* __restrict__ cnt, int* __restrict__ posArr)
{
    int e = blockIdx.x * 256 + threadIdx.x;
    if (e < NE) posArr[e] = atomicAdd(&cnt[ei[e]], 1);
}

__global__ __launch_bounds__(SCAN_B) void scan1_kernel(
    const int* __restrict__ cnt, int* __restrict__ bsum)
{
    int i = blockIdx.x * SCAN_B + threadIdx.x;
    int v = (i < NN) ? cnt[i] : 0;
#pragma unroll
    for (int off = 32; off > 0; off >>= 1) v += __shfl_down(v, off, 64);
    __shared__ int wsum[16];
    int wave = threadIdx.x >> 6, lane = threadIdx.x & 63;
    if (lane == 0) wsum[wave] = v;
    __syncthreads();
    if (threadIdx.x == 0) {
        int s = 0;
#pragma unroll
        for (int w = 0; w < 16; w++) s += wsum[w];
        bsum[blockIdx.x] = s;
    }
}

// scan with block-prefix folded in; off aliases cnt (read-before-write per block)
__global__ __launch_bounds__(SCAN_B) void scan3_kernel(
    const int* cnt, const int* __restrict__ bsum, int* off)
{
    __shared__ int sarr[NBLK_SCAN];
    __shared__ int sbase;
    int t = threadIdx.x;
    if (t < NBLK_SCAN) sarr[t] = bsum[t];
    __syncthreads();
    if (t == 0) {
        int s = 0;
        for (int b = 0; b < (int)blockIdx.x; b++) s += sarr[b];
        sbase = s;
    }

    __shared__ int buf[2][SCAN_B];
    int i = blockIdx.x * SCAN_B + t;
    int v = (i < NN) ? cnt[i] : 0;
    buf[0][t] = v;
    __syncthreads();
    int src = 0;
    for (int d = 1; d < SCAN_B; d <<= 1) {
        int nv = buf[src][t] + ((t >= d) ? buf[src][t - d] : 0);
        buf[src ^ 1][t] = nv;
        src ^= 1;
        __syncthreads();
    }
    if (i < NN) off[i] = sbase + buf[src][t] - v;   // exclusive
    if (blockIdx.x == NBLK_SCAN - 1 && t == SCAN_B - 1)
        off[NN] = sbase + buf[src][t];              // total = NE
}

// row-sorted records {row, col, ea0, ea1}: ONE 16B scatter per edge
__global__ __launch_bounds__(256) void fill2_kernel(
    const int* __restrict__ ei, const int* __restrict__ posArr,
    const int* __restrict__ off, const float* __restrict__ eattr,
    float4* __restrict__ rec)
{
    int e = blockIdx.x * 256 + threadIdx.x;
    if (e < NE) {
        int row = ei[e];
        int j = off[row] + posArr[e];
        float2 ea = reinterpret_cast<const float2*>(eattr)[e];
        float4 v;
        v.x = __int_as_float(row);
        v.y = __int_as_float(ei[NE + e]);
        v.z = ea.x; v.w = ea.y;
        rec[j] = v;
    }
}

// ---- P precompute for layer 0: Pr[i]=x[i]@W1[1:9], Pc[i]=x[i]@W1[9:17] ------
__global__ __launch_bounds__(256) void prep_kernel(
    const float* __restrict__ x, const float* __restrict__ W1,
    float* __restrict__ Pr, float* __restrict__ Pc)
{
    int i = blockIdx.x * 256 + threadIdx.x;
    if (i >= NN) return;
    const float4* xi = reinterpret_cast<const float4*>(x + (size_t)i * 8);
    float4 a0 = xi[0], a1 = xi[1];
    float xv[8] = {a0.x, a0.y, a0.z, a0.w, a1.x, a1.y, a1.z, a1.w};
    float pr[16], pc[16];
#pragma unroll
    for (int q = 0; q < 16; q++) { pr[q] = 0.f; pc[q] = 0.f; }
#pragma unroll
    for (int k = 0; k < 8; k++) {
        float v = xv[k];
#pragma unroll
        for (int q = 0; q < 16; q++) {
            pr[q] += v * W1[(1 + k) * 16 + q];
            pc[q] += v * W1[(9 + k) * 16 + q];
        }
    }
    float4* po = reinterpret_cast<float4*>(Pr + (size_t)i * 16);
#pragma unroll
    for (int t = 0; t < 4; t++)
        po[t] = make_float4(pr[4 * t], pr[4 * t + 1], pr[4 * t + 2], pr[4 * t + 3]);
    float4* qo = reinterpret_cast<float4*>(Pc + (size_t)i * 16);
#pragma unroll
    for (int t = 0; t < 4; t++)
        qo[t] = make_float4(pc[4 * t], pc[4 * t + 1], pc[4 * t + 2], pc[4 * t + 3]);
}

// ============ FUSED layer kernel: edge MLP + LDS aggregate + node MLP ========
// Block b owns nodes [256b, 256b+256) AND their contiguous edge range
// off[n0]..off[n1] (row-sorted CSR). Phase 1: edge MLPs (ein always rec.zw;
// output either rewrites rec as {row,col,o0,o1} or, last layer, stays local),
// aggregates into LDS via ds_add_f32. Phase 2: node MLP from LDS agg; writes
// xout and (HAS_NEXT) next layer's Pr/Pc into the *other* P buffer pair.
template <bool WRITE_REC, bool NEED_SUM, bool HAS_NEXT>
__global__ __launch_bounds__(256, 4) void fused_kernel(
    float4* __restrict__ rec, const int* __restrict__ off,
    const float* __restrict__ PrIn, const float* __restrict__ PcIn,
    const float* __restrict__ gptr,
    const float* __restrict__ eW1, const float* __restrict__ eB1,
    const float* __restrict__ eW2, const float* __restrict__ eB2,
    const float* __restrict__ x,
    const float* __restrict__ nW1, const float* __restrict__ nB1,
    const float* __restrict__ nW2, const float* __restrict__ nB2,
    const float* __restrict__ nextW1,
    float* __restrict__ PrOut, float* __restrict__ PcOut,
    float* __restrict__ xout, float* __restrict__ sums)
{
    __shared__ float sagg[256][2];
    __shared__ float redE[4][2];
    __shared__ float redN[4][8];
    int tid = threadIdx.x;
    sagg[tid][0] = 0.f; sagg[tid][1] = 0.f;
    __syncthreads();

    int n0 = blockIdx.x * 256;
    int nEnd = n0 + 256; if (nEnd > NN) nEnd = NN;
    int e0 = off[n0], e1 = off[nEnd];

    float gval = gptr[0];
    float gterm[16];
#pragma unroll
    for (int q = 0; q < 16; q++) gterm[q] = eB1[q] + gval * eW1[q];

    float t0 = 0.f, t1 = 0.f;
    for (int e = e0 + tid; e < e1; e += 256) {
        float4 r = rec[e];
        int row = __float_as_int(r.x);
        int col = __float_as_int(r.y);
        float ea0 = r.z, ea1 = r.w;
        const float4* pr = reinterpret_cast<const float4*>(PrIn + (size_t)row * 16);
        const float4* pc = reinterpret_cast<const float4*>(PcIn + (size_t)col * 16);
        float4 r0 = pr[0], r1 = pr[1], r2 = pr[2], r3 = pr[3];
        float4 c0 = pc[0], c1 = pc[1], c2 = pc[2], c3 = pc[3];
        float h[16];
        h[0]  = gterm[0]  + r0.x + c0.x;
        h[1]  = gterm[1]  + r0.y + c0.y;
        h[2]  = gterm[2]  + r0.z + c0.z;
        h[3]  = gterm[3]  + r0.w + c0.w;
        h[4]  = gterm[4]  + r1.x + c1.x;
        h[5]  = gterm[5]  + r1.y + c1.y;
        h[6]  = gterm[6]  + r1.z + c1.z;
        h[7]  = gterm[7]  + r1.w + c1.w;
        h[8]  = gterm[8]  + r2.x + c2.x;
        h[9]  = gterm[9]  + r2.y + c2.y;
        h[10] = gterm[10] + r2.z + c2.z;
        h[11] = gterm[11] + r2.w + c2.w;
        h[12] = gterm[12] + r3.x + c3.x;
        h[13] = gterm[13] + r3.y + c3.y;
        h[14] = gterm[14] + r3.z + c3.z;
        h[15] = gterm[15] + r3.w + c3.w;
#pragma unroll
        for (int q = 0; q < 16; q++) {
            h[q] += ea0 * eW1[17 * 16 + q];
            h[q] += ea1 * eW1[18 * 16 + q];
        }
        float s0 = eB2[0], s1 = eB2[1];
#pragma unroll
        for (int q = 0; q < 16; q++) {
            float rr = fmaxf(h[q], 0.f);
            s0 += rr * eW2[2 * q];
            s1 += rr * eW2[2 * q + 1];
        }
        if (WRITE_REC) {
            float4 w;
            w.x = r.x; w.y = r.y; w.z = s0; w.w = s1;
            rec[e] = w;
        }
        int li = row - n0;
        atomicAdd(&sagg[li][0], s0);
        atomicAdd(&sagg[li][1], s1);
        t0 += s0; t1 += s1;
    }

    if (NEED_SUM) {
        float r0 = wave_red(t0);
        float r1 = wave_red(t1);
        int wave = tid >> 6, lane = tid & 63;
        if (lane == 0) { redE[wave][0] = r0; redE[wave][1] = r1; }
    }
    __syncthreads();   // sagg complete (and redE visible)
    if (NEED_SUM && tid == 0) {
        atomicAdd(&sums[0], redE[0][0] + redE[1][0] + redE[2][0] + redE[3][0]);
        atomicAdd(&sums[1], redE[0][1] + redE[1][1] + redE[2][1] + redE[3][1]);
    }

    // ---------------- phase 2: node MLP ----------------
    int n = n0 + tid;
    float out[8];
#pragma unroll
    for (int m = 0; m < 8; m++) out[m] = 0.f;

    if (n < NN) {
        float in[11];
        in[0] = gval;
        const float4* xi = reinterpret_cast<const float4*>(x + (size_t)n * 8);
        float4 a0 = xi[0], a1 = xi[1];
        in[1] = a0.x; in[2] = a0.y; in[3] = a0.z; in[4] = a0.w;
        in[5] = a1.x; in[6] = a1.y; in[7] = a1.z; in[8] = a1.w;
        in[9] = sagg[tid][0]; in[10] = sagg[tid][1];

        float h[16];
#pragma unroll
        for (int q = 0; q < 16; q++) h[q] = nB1[q];
#pragma unroll
        for (int k = 0; k < 11; k++) {
            float v = in[k];
#pragma unroll
            for (int q = 0; q < 16; q++) h[q] += v * nW1[k * 16 + q];
        }
#pragma unroll
        for (int m = 0; m < 8; m++) out[m] = nB2[m];
#pragma unroll
        for (int q = 0; q < 16; q++) {
            float hq = fmaxf(h[q], 0.f);
#pragma unroll
            for (int m = 0; m < 8; m++) out[m] += hq * nW2[q * 8 + m];
        }
        float4* xo = reinterpret_cast<float4*>(xout + (size_t)n * 8);
        xo[0] = make_float4(out[0], out[1], out[2], out[3]);
        xo[1] = make_float4(out[4], out[5], out[6], out[7]);

        if (HAS_NEXT) {
            float pr[16], pc[16];
#pragma unroll
            for (int q = 0; q < 16; q++) { pr[q] = 0.f; pc[q] = 0.f; }
#pragma unroll
            for (int k = 0; k < 8; k++) {
                float v = out[k];
#pragma unroll
                for (int q = 0; q < 16; q++) {
                    pr[q] += v * nextW1[(1 + k) * 16 + q];
                    pc[q] += v * nextW1[(9 + k) * 16 + q];
                }
            }
            float4* po = reinterpret_cast<float4*>(PrOut + (size_t)n * 16);
#pragma unroll
            for (int t = 0; t < 4; t++)
                po[t] = make_float4(pr[4*t], pr[4*t+1], pr[4*t+2], pr[4*t+3]);
            float4* qo = reinterpret_cast<float4*>(PcOut + (size_t)n * 16);
#pragma unroll
            for (int t = 0; t < 4; t++)
                qo[t] = make_float4(pc[4*t], pc[4*t+1], pc[4*t+2], pc[4*t+3]);
        }
    }
    if (NEED_SUM) {
        float r[8];
#pragma unroll
        for (int m = 0; m < 8; m++) r[m] = wave_red(out[m]);
        int wave = tid >> 6, lane = tid & 63;
        if (lane == 0) {
#pragma unroll
            for (int m = 0; m < 8; m++) redN[wave][m] = r[m];
        }
        __syncthreads();
        if (tid == 0) {
#pragma unroll
            for (int m = 0; m < 8; m++) {
                float s = redN[0][m] + redN[1][m] + redN[2][m] + redN[3][m];
                atomicAdd(&sums[2 + m], s);
            }
        }
    }
}

// ---------------- global block: MLP(11->16->1), single thread ----------------
__global__ void glob_kernel(const float* __restrict__ sums,
                            const float* __restrict__ gold,
                            const float* __restrict__ W1, const float* __restrict__ B1,
                            const float* __restrict__ W2, const float* __restrict__ B2,
                            float* __restrict__ gnew)
{
    if (threadIdx.x == 0 && blockIdx.x == 0) {
        float in[11];
#pragma unroll
        for (int j = 0; j < 8; j++) in[j] = sums[2 + j] * (1.0f / NN);
        in[8] = sums[0] * (1.0f / NE);
        in[9] = sums[1] * (1.0f / NE);
        in[10] = gold[0];
        float acc = B2[0];
#pragma unroll
        for (int j = 0; j < 16; j++) {
            float h = B1[j];
#pragma unroll
            for (int k = 0; k < 11; k++) h += in[k] * W1[k * 16 + j];
            acc += fmaxf(h, 0.f) * W2[j];
        }
        gnew[0] = acc;
    }
}

extern "C" void kernel_launch(void* const* d_in, const int* in_sizes, int n_in,
                              void* d_out, int out_size, void* d_ws, size_t ws_size,
                              hipStream_t stream) {
    const float* x     = (const float*)d_in[0];
    const int*   ei    = (const int*)d_in[1];
    const float* eattr = (const float*)d_in[2];
    const float* g     = (const float*)d_in[3];
    const float* eW1 = (const float*)d_in[4];
    const float* eB1 = (const float*)d_in[5];
    const float* eW2 = (const float*)d_in[6];
    const float* eB2 = (const float*)d_in[7];
    const float* nW1 = (const float*)d_in[8];
    const float* nB1 = (const float*)d_in[9];
    const float* nW2 = (const float*)d_in[10];
    const float* nB2 = (const float*)d_in[11];
    const float* gW1 = (const float*)d_in[12];
    const float* gB1 = (const float*)d_in[13];
    const float* gW2 = (const float*)d_in[14];
    const float* gB2 = (const float*)d_in[15];
    float* out = (float*)d_out;

    char* ws = (char*)d_ws;
    float*  xb0    = (float*)(ws);                 // 3,200,000
    int*    off    = (int*)  (ws + 3200000);       // 400,004 (aliases cnt)
    int*    cnt    = off;
    int*    bsum   = (int*)  (ws + 3600064);       // 392
    float*  sums   = (float*)(ws + 3600512);       // 2 slabs x 16 floats
    float*  g1     = (float*)(ws + 3600640);
    float*  g2     = g1 + 1;
    float4* rec    = (float4*)(ws + 3600704);      // 25,600,000 -> 29,200,704
    float*  PrA    = (float*)(ws + 29200704);      // 6,400,000
    float*  PcA    = (float*)(ws + 35600704);      // 6,400,000
    float*  PrB    = (float*)(ws + 42000704);      // 6,400,000 (aliases posArr)
    int*    posArr = (int*)  PrB;
    float*  PcB    = (float*)(ws + 48400704);      // 6,400,000 -> ends 54,800,704
    float*  xb1    = out;                          // d_out doubles as x buffer

    dim3 blk(256);
    dim3 egrid(NE / 256);                          // 6250 (build/fill)
    dim3 ngrid((NN + 255) / 256);                  // 391 (prep + fused layers)

    // ---- build row-sorted packed records (once per call) ----
    hipMemsetAsync(cnt, 0, 400000, stream);
    hipMemsetAsync(sums, 0, 192, stream);          // sums + g1/g2
    build1_kernel<<<egrid, blk, 0, stream>>>(ei, cnt, posArr);
    scan1_kernel<<<NBLK_SCAN, SCAN_B, 0, stream>>>(cnt, bsum);
    scan3_kernel<<<NBLK_SCAN, SCAN_B, 0, stream>>>(cnt, bsum, off);
    fill2_kernel<<<egrid, blk, 0, stream>>>(ei, posArr, off, eattr, rec);
    prep_kernel<<<ngrid, blk, 0, stream>>>(x, eW1, PrA, PcA);   // posArr dead after fill2

    // ---- layer 0: P=A -> writes P=B; rec.zw: ea -> L0 edge emb; x -> xb0 ----
    fused_kernel<true, true, true><<<ngrid, blk, 0, stream>>>(
        rec, off, PrA, PcA, g,
        eW1, eB1, eW2, eB2,
        x, nW1, nB1, nW2, nB2,
        eW1 + 304, PrB, PcB, xb0, sums);
    glob_kernel<<<1, 64, 0, stream>>>(sums, g, gW1, gB1, gW2, gB2, g1);

    // ---- layer 1: P=B -> writes P=A; rec.zw: L0 -> L1 emb; xb0 -> d_out ----
    fused_kernel<true, true, true><<<ngrid, blk, 0, stream>>>(
        rec, off, PrB, PcB, g1,
        eW1 + 304, eB1 + 16, eW2 + 32, eB2 + 2,
        xb0, nW1 + 176, nB1 + 16, nW2 + 128, nB2 + 8,
        eW1 + 608, PrA, PcA, xb1, sums + 16);
    glob_kernel<<<1, 64, 0, stream>>>(sums + 16, g1, gW1 + 176, gB1 + 16, gW2 + 16, gB2 + 1, g2);

    // ---- layer 2: P=A; no rec rewrite, no P out; d_out -> d_out ----
    fused_kernel<false, false, false><<<ngrid, blk, 0, stream>>>(
        rec, off, PrA, PcA, g2,
        eW1 + 608, eB1 + 32, eW2 + 64, eB2 + 4,
        xb1, nW1 + 352, nB1 + 32, nW2 + 256, nB2 + 16,
        nullptr, nullptr, nullptr, out, sums);
}

// Round 15
// 388.790 us; speedup vs baseline: 1.1586x; 1.0278x over previous
//
#include <hip/hip_runtime.h>

#define NN 100000
#define NE 1600000
#define SCAN_B 1024
#define NBLK_SCAN ((NN + SCAN_B - 1) / SCAN_B)   // 98
#define ECAP 5120                                // LDS eval slots per block (+16 sigma)

__device__ __forceinline__ float wave_red(float v) {
#pragma unroll
    for (int off = 32; off > 0; off >>= 1) v += __shfl_down(v, off, 64);
    return v;
}

// ---------------- build phase (once per call) --------------------------------
__global__ __launch_bounds__(256) void build1_kernel(
    const int* __restrict__ ei, int* __restrict__ cnt, int* __restrict__ posArr)
{
    int e = blockIdx.x * 256 + threadIdx.x;
    if (e < NE) posArr[e] = atomicAdd(&cnt[ei[e]], 1);
}

__global__ __launch_bounds__(SCAN_B) void scan1_kernel(
    const int* __restrict__ cnt, int* __restrict__ bsum)
{
    int i = blockIdx.x * SCAN_B + threadIdx.x;
    int v = (i < NN) ? cnt[i] : 0;
#pragma unroll
    for (int off = 32; off > 0; off >>= 1) v += __shfl_down(v, off, 64);
    __shared__ int wsum[16];
    int wave = threadIdx.x >> 6, lane = threadIdx.x & 63;
    if (lane == 0) wsum[wave] = v;
    __syncthreads();
    if (threadIdx.x == 0) {
        int s = 0;
#pragma unroll
        for (int w = 0; w < 16; w++) s += wsum[w];
        bsum[blockIdx.x] = s;
    }
}

// scan with block-prefix folded in; off aliases cnt (read-before-write per block)
__global__ __launch_bounds__(SCAN_B) void scan3_kernel(
    const int* cnt, const int* __restrict__ bsum, int* off)
{
    __shared__ int sarr[NBLK_SCAN];
    __shared__ int sbase;
    int t = threadIdx.x;
    if (t < NBLK_SCAN) sarr[t] = bsum[t];
    __syncthreads();
    if (t == 0) {
        int s = 0;
        for (int b = 0; b < (int)blockIdx.x; b++) s += sarr[b];
        sbase = s;
    }

    __shared__ int buf[2][SCAN_B];
    int i = blockIdx.x * SCAN_B + t;
    int v = (i < NN) ? cnt[i] : 0;
    buf[0][t] = v;
    __syncthreads();
    int src = 0;
    for (int d = 1; d < SCAN_B; d <<= 1) {
        int nv = buf[src][t] + ((t >= d) ? buf[src][t - d] : 0);
        buf[src ^ 1][t] = nv;
        src ^= 1;
        __syncthreads();
    }
    if (i < NN) off[i] = sbase + buf[src][t] - v;   // exclusive
    if (blockIdx.x == NBLK_SCAN - 1 && t == SCAN_B - 1)
        off[NN] = sbase + buf[src][t];              // total = NE
}

// row-sorted records {row, col, ea0, ea1}: ONE 16B scatter per edge
__global__ __launch_bounds__(256) void fill2_kernel(
    const int* __restrict__ ei, const int* __restrict__ posArr,
    const int* __restrict__ off, const float* __restrict__ eattr,
    float4* __restrict__ rec)
{
    int e = blockIdx.x * 256 + threadIdx.x;
    if (e < NE) {
        int row = ei[e];
        int j = off[row] + posArr[e];
        float2 ea = reinterpret_cast<const float2*>(eattr)[e];
        float4 v;
        v.x = __int_as_float(row);
        v.y = __int_as_float(ei[NE + e]);
        v.z = ea.x; v.w = ea.y;
        rec[j] = v;
    }
}

// ---- P precompute for layer 0: Pr[i]=x[i]@W1[1:9], Pc[i]=x[i]@W1[9:17] ------
__global__ __launch_bounds__(256) void prep_kernel(
    const float* __restrict__ x, const float* __restrict__ W1,
    float* __restrict__ Pr, float* __restrict__ Pc)
{
    int i = blockIdx.x * 256 + threadIdx.x;
    if (i >= NN) return;
    const float4* xi = reinterpret_cast<const float4*>(x + (size_t)i * 8);
    float4 a0 = xi[0], a1 = xi[1];
    float xv[8] = {a0.x, a0.y, a0.z, a0.w, a1.x, a1.y, a1.z, a1.w};
    float pr[16], pc[16];
#pragma unroll
    for (int q = 0; q < 16; q++) { pr[q] = 0.f; pc[q] = 0.f; }
#pragma unroll
    for (int k = 0; k < 8; k++) {
        float v = xv[k];
#pragma unroll
        for (int q = 0; q < 16; q++) {
            pr[q] += v * W1[(1 + k) * 16 + q];
            pc[q] += v * W1[(9 + k) * 16 + q];
        }
    }
    float4* po = reinterpret_cast<float4*>(Pr + (size_t)i * 16);
#pragma unroll
    for (int t = 0; t < 4; t++)
        po[t] = make_float4(pr[4 * t], pr[4 * t + 1], pr[4 * t + 2], pr[4 * t + 3]);
    float4* qo = reinterpret_cast<float4*>(Pc + (size_t)i * 16);
#pragma unroll
    for (int t = 0; t < 4; t++)
        qo[t] = make_float4(pc[4 * t], pc[4 * t + 1], pc[4 * t + 2], pc[4 * t + 3]);
}

// ============ FUSED layer kernel: edge MLP + LDS eval array + node MLP =======
// Block b owns nodes [256b, 256b+256) AND their contiguous edge range.
// Phase 1: edge MLPs write (s0,s1) to seval[e-e0] (plain ds_write — NO LDS
// atomics; r14's same-address atomic serialization was the +25us). Overflow
// edges (k>=ECAP, ~never) fall back to sagg atomics for correctness.
// Phase 2: thread=node sums its contiguous seval range, then node MLP.
template <bool WRITE_REC, bool NEED_SUM, bool HAS_NEXT>
__global__ __launch_bounds__(256, 3) void fused_kernel(
    float4* __restrict__ rec, const int* __restrict__ off,
    const float* __restrict__ PrIn, const float* __restrict__ PcIn,
    const float* __restrict__ gptr,
    const float* __restrict__ eW1, const float* __restrict__ eB1,
    const float* __restrict__ eW2, const float* __restrict__ eB2,
    const float* __restrict__ x,
    const float* __restrict__ nW1, const float* __restrict__ nB1,
    const float* __restrict__ nW2, const float* __restrict__ nB2,
    const float* __restrict__ nextW1,
    float* __restrict__ PrOut, float* __restrict__ PcOut,
    float* __restrict__ xout, float* __restrict__ sums)
{
    __shared__ float seval[ECAP * 2];            // 40 KB
    __shared__ float sagg[256][2];               // overflow fallback
    __shared__ float redE[4][2];
    __shared__ float redN[4][8];
    int tid = threadIdx.x;
    sagg[tid][0] = 0.f; sagg[tid][1] = 0.f;
    __syncthreads();

    int n0 = blockIdx.x * 256;
    int nEnd = n0 + 256; if (nEnd > NN) nEnd = NN;
    int e0 = off[n0], e1 = off[nEnd];

    float gval = gptr[0];
    float gterm[16];
#pragma unroll
    for (int q = 0; q < 16; q++) gterm[q] = eB1[q] + gval * eW1[q];

    float t0 = 0.f, t1 = 0.f;
    for (int e = e0 + tid; e < e1; e += 256) {
        float4 r = rec[e];
        int row = __float_as_int(r.x);
        int col = __float_as_int(r.y);
        float ea0 = r.z, ea1 = r.w;
        const float4* pr = reinterpret_cast<const float4*>(PrIn + (size_t)row * 16);
        const float4* pc = reinterpret_cast<const float4*>(PcIn + (size_t)col * 16);
        float4 r0 = pr[0], r1 = pr[1], r2 = pr[2], r3 = pr[3];
        float4 c0 = pc[0], c1 = pc[1], c2 = pc[2], c3 = pc[3];
        float h[16];
        h[0]  = gterm[0]  + r0.x + c0.x;
        h[1]  = gterm[1]  + r0.y + c0.y;
        h[2]  = gterm[2]  + r0.z + c0.z;
        h[3]  = gterm[3]  + r0.w + c0.w;
        h[4]  = gterm[4]  + r1.x + c1.x;
        h[5]  = gterm[5]  + r1.y + c1.y;
        h[6]  = gterm[6]  + r1.z + c1.z;
        h[7]  = gterm[7]  + r1.w + c1.w;
        h[8]  = gterm[8]  + r2.x + c2.x;
        h[9]  = gterm[9]  + r2.y + c2.y;
        h[10] = gterm[10] + r2.z + c2.z;
        h[11] = gterm[11] + r2.w + c2.w;
        h[12] = gterm[12] + r3.x + c3.x;
        h[13] = gterm[13] + r3.y + c3.y;
        h[14] = gterm[14] + r3.z + c3.z;
        h[15] = gterm[15] + r3.w + c3.w;
#pragma unroll
        for (int q = 0; q < 16; q++) {
            h[q] += ea0 * eW1[17 * 16 + q];
            h[q] += ea1 * eW1[18 * 16 + q];
        }
        float s0 = eB2[0], s1 = eB2[1];
#pragma unroll
        for (int q = 0; q < 16; q++) {
            float rr = fmaxf(h[q], 0.f);
            s0 += rr * eW2[2 * q];
            s1 += rr * eW2[2 * q + 1];
        }
        if (WRITE_REC) {
            float4 w;
            w.x = r.x; w.y = r.y; w.z = s0; w.w = s1;
            rec[e] = w;
        }
        int k = e - e0;
        if (k < ECAP) {
            seval[2 * k]     = s0;
            seval[2 * k + 1] = s1;
        } else {                                  // ~never: Poisson +16 sigma
            int li = row - n0;
            atomicAdd(&sagg[li][0], s0);
            atomicAdd(&sagg[li][1], s1);
        }
        t0 += s0; t1 += s1;
    }

    if (NEED_SUM) {
        float r0 = wave_red(t0);
        float r1 = wave_red(t1);
        int wave = tid >> 6, lane = tid & 63;
        if (lane == 0) { redE[wave][0] = r0; redE[wave][1] = r1; }
    }
    __syncthreads();   // seval/sagg complete (and redE visible)
    if (NEED_SUM && tid == 0) {
        atomicAdd(&sums[0], redE[0][0] + redE[1][0] + redE[2][0] + redE[3][0]);
        atomicAdd(&sums[1], redE[0][1] + redE[1][1] + redE[2][1] + redE[3][1]);
    }

    // ---------------- phase 2: node MLP ----------------
    int n = n0 + tid;
    float out[8];
#pragma unroll
    for (int m = 0; m < 8; m++) out[m] = 0.f;

    if (n < NN) {
        float in[11];
        in[0] = gval;
        const float4* xi = reinterpret_cast<const float4*>(x + (size_t)n * 8);
        float4 a0 = xi[0], a1 = xi[1];
        in[1] = a0.x; in[2] = a0.y; in[3] = a0.z; in[4] = a0.w;
        in[5] = a1.x; in[6] = a1.y; in[7] = a1.z; in[8] = a1.w;

        // segmented sum over this node's contiguous seval range
        int a0i = off[n] - e0;
        int a1i = off[n + 1] - e0;
        if (a1i > ECAP) a1i = ECAP;
        float s0 = sagg[tid][0], s1 = sagg[tid][1];
        for (int k = a0i; k < a1i; k++) {
            s0 += seval[2 * k];
            s1 += seval[2 * k + 1];
        }
        in[9] = s0; in[10] = s1;

        float h[16];
#pragma unroll
        for (int q = 0; q < 16; q++) h[q] = nB1[q];
#pragma unroll
        for (int k = 0; k < 11; k++) {
            float v = in[k];
#pragma unroll
            for (int q = 0; q < 16; q++) h[q] += v * nW1[k * 16 + q];
        }
#pragma unroll
        for (int m = 0; m < 8; m++) out[m] = nB2[m];
#pragma unroll
        for (int q = 0; q < 16; q++) {
            float hq = fmaxf(h[q], 0.f);
#pragma unroll
            for (int m = 0; m < 8; m++) out[m] += hq * nW2[q * 8 + m];
        }
        float4* xo = reinterpret_cast<float4*>(xout + (size_t)n * 8);
        xo[0] = make_float4(out[0], out[1], out[2], out[3]);
        xo[1] = make_float4(out[4], out[5], out[6], out[7]);

        if (HAS_NEXT) {
            float pr[16], pc[16];
#pragma unroll
            for (int q = 0; q < 16; q++) { pr[q] = 0.f; pc[q] = 0.f; }
#pragma unroll
            for (int k = 0; k < 8; k++) {
                float v = out[k];
#pragma unroll
                for (int q = 0; q < 16; q++) {
                    pr[q] += v * nextW1[(1 + k) * 16 + q];
                    pc[q] += v * nextW1[(9 + k) * 16 + q];
                }
            }
            float4* po = reinterpret_cast<float4*>(PrOut + (size_t)n * 16);
#pragma unroll
            for (int t = 0; t < 4; t++)
                po[t] = make_float4(pr[4*t], pr[4*t+1], pr[4*t+2], pr[4*t+3]);
            float4* qo = reinterpret_cast<float4*>(PcOut + (size_t)n * 16);
#pragma unroll
            for (int t = 0; t < 4; t++)
                qo[t] = make_float4(pc[4*t], pc[4*t+1], pc[4*t+2], pc[4*t+3]);
        }
    }
    if (NEED_SUM) {
        float r[8];
#pragma unroll
        for (int m = 0; m < 8; m++) r[m] = wave_red(out[m]);
        int wave = tid >> 6, lane = tid & 63;
        if (lane == 0) {
#pragma unroll
            for (int m = 0; m < 8; m++) redN[wave][m] = r[m];
        }
        __syncthreads();
        if (tid == 0) {
#pragma unroll
            for (int m = 0; m < 8; m++) {
                float s = redN[0][m] + redN[1][m] + redN[2][m] + redN[3][m];
                atomicAdd(&sums[2 + m], s);
            }
        }
    }
}

// ---------------- global block: MLP(11->16->1), single thread ----------------
__global__ void glob_kernel(const float* __restrict__ sums,
                            const float* __restrict__ gold,
                            const float* __restrict__ W1, const float* __restrict__ B1,
                            const float* __restrict__ W2, const float* __restrict__ B2,
                            float* __restrict__ gnew)
{
    if (threadIdx.x == 0 && blockIdx.x == 0) {
        float in[11];
#pragma unroll
        for (int j = 0; j < 8; j++) in[j] = sums[2 + j] * (1.0f / NN);
        in[8] = sums[0] * (1.0f / NE);
        in[9] = sums[1] * (1.0f / NE);
        in[10] = gold[0];
        float acc = B2[0];
#pragma unroll
        for (int j = 0; j < 16; j++) {
            float h = B1[j];
#pragma unroll
            for (int k = 0; k < 11; k++) h += in[k] * W1[k * 16 + j];
            acc += fmaxf(h, 0.f) * W2[j];
        }
        gnew[0] = acc;
    }
}

extern "C" void kernel_launch(void* const* d_in, const int* in_sizes, int n_in,
                              void* d_out, int out_size, void* d_ws, size_t ws_size,
                              hipStream_t stream) {
    const float* x     = (const float*)d_in[0];
    const int*   ei    = (const int*)d_in[1];
    const float* eattr = (const float*)d_in[2];
    const float* g     = (const float*)d_in[3];
    const float* eW1 = (const float*)d_in[4];
    const float* eB1 = (const float*)d_in[5];
    const float* eW2 = (const float*)d_in[6];
    const float* eB2 = (const float*)d_in[7];
    const float* nW1 = (const float*)d_in[8];
    const float* nB1 = (const float*)d_in[9];
    const float* nW2 = (const float*)d_in[10];
    const float* nB2 = (const float*)d_in[11];
    const float* gW1 = (const float*)d_in[12];
    const float* gB1 = (const float*)d_in[13];
    const float* gW2 = (const float*)d_in[14];
    const float* gB2 = (const float*)d_in[15];
    float* out = (float*)d_out;

    char* ws = (char*)d_ws;
    float*  xb0    = (float*)(ws);                 // 3,200,000
    int*    off    = (int*)  (ws + 3200000);       // 400,004 (aliases cnt)
    int*    cnt    = off;
    int*    bsum   = (int*)  (ws + 3600064);       // 392
    float*  sums   = (float*)(ws + 3600512);       // 2 slabs x 16 floats
    float*  g1     = (float*)(ws + 3600640);
    float*  g2     = g1 + 1;
    float4* rec    = (float4*)(ws + 3600704);      // 25,600,000 -> 29,200,704
    float*  PrA    = (float*)(ws + 29200704);      // 6,400,000
    float*  PcA    = (float*)(ws + 35600704);      // 6,400,000
    float*  PrB    = (float*)(ws + 42000704);      // 6,400,000 (aliases posArr)
    int*    posArr = (int*)  PrB;
    float*  PcB    = (float*)(ws + 48400704);      // 6,400,000 -> ends 54,800,704
    float*  xb1    = out;                          // d_out doubles as x buffer

    dim3 blk(256);
    dim3 egrid(NE / 256);                          // 6250 (build/fill)
    dim3 ngrid((NN + 255) / 256);                  // 391 (prep + fused layers)

    // ---- build row-sorted packed records (once per call) ----
    hipMemsetAsync(cnt, 0, 400000, stream);
    hipMemsetAsync(sums, 0, 192, stream);          // sums + g1/g2
    build1_kernel<<<egrid, blk, 0, stream>>>(ei, cnt, posArr);
    scan1_kernel<<<NBLK_SCAN, SCAN_B, 0, stream>>>(cnt, bsum);
    scan3_kernel<<<NBLK_SCAN, SCAN_B, 0, stream>>>(cnt, bsum, off);
    fill2_kernel<<<egrid, blk, 0, stream>>>(ei, posArr, off, eattr, rec);
    prep_kernel<<<ngrid, blk, 0, stream>>>(x, eW1, PrA, PcA);   // posArr dead after fill2

    // ---- layer 0: P=A -> writes P=B; rec.zw: ea -> L0 edge emb; x -> xb0 ----
    fused_kernel<true, true, true><<<ngrid, blk, 0, stream>>>(
        rec, off, PrA, PcA, g,
        eW1, eB1, eW2, eB2,
        x, nW1, nB1, nW2, nB2,
        eW1 + 304, PrB, PcB, xb0, sums);
    glob_kernel<<<1, 64, 0, stream>>>(sums, g, gW1, gB1, gW2, gB2, g1);

    // ---- layer 1: P=B -> writes P=A; rec.zw: L0 -> L1 emb; xb0 -> d_out ----
    fused_kernel<true, true, true><<<ngrid, blk, 0, stream>>>(
        rec, off, PrB, PcB, g1,
        eW1 + 304, eB1 + 16, eW2 + 32, eB2 + 2,
        xb0, nW1 + 176, nB1 + 16, nW2 + 128, nB2 + 8,
        eW1 + 608, PrA, PcA, xb1, sums + 16);
    glob_kernel<<<1, 64, 0, stream>>>(sums + 16, g1, gW1 + 176, gB1 + 16, gW2 + 16, gB2 + 1, g2);

    // ---- layer 2: P=A; no rec rewrite, no P out; d_out -> d_out ----
    fused_kernel<false, false, false><<<ngrid, blk, 0, stream>>>(
        rec, off, PrA, PcA, g2,
        eW1 + 608, eB1 + 32, eW2 + 64, eB2 + 4,
        xb1, nW1 + 352, nB1 + 32, nW2 + 256, nB2 + 16,
        nullptr, nullptr, nullptr, out, sums);
}

// Round 16
// 370.338 us; speedup vs baseline: 1.2163x; 1.0498x over previous
//
#include <hip/hip_runtime.h>

#define NN 100000
#define NE 1600000
#define CH 4096                                  // edges per chunk
#define NCHUNK ((NE + CH - 1) / CH)              // 391
#define NBUCK ((NN + 255) / 256)                 // 391 (256-node buckets = fused blocks)

__device__ __forceinline__ float wave_red(float v) {
#pragma unroll
    for (int off = 32; off > 0; off >>= 1) v += __shfl_down(v, off, 64);
    return v;
}

// ---------------- build phase: bucket sort, zero global atomics --------------
// A) per-chunk histogram over 391 buckets (LDS atomics only)
__global__ __launch_bounds__(256) void hist_kernel(
    const int* __restrict__ ei, int* __restrict__ hist)
{
    __shared__ int h[NBUCK];
    int t = threadIdx.x, c = blockIdx.x;
    for (int b = t; b < NBUCK; b += 256) h[b] = 0;
    __syncthreads();
    int base = c * CH;
    for (int i = t; i < CH; i += 256) {
        int e = base + i;
        if (e < NE) atomicAdd(&h[ei[e] >> 8], 1);
    }
    __syncthreads();
    for (int b = t; b < NBUCK; b += 256) hist[c * NBUCK + b] = h[b];
}

// B) per-bucket exclusive scan over chunks -> baseT[b][c]; bucket totals
__global__ __launch_bounds__(512) void bscan_kernel(
    const int* __restrict__ hist, int* __restrict__ baseT, int* __restrict__ colTotal)
{
    __shared__ int buf[2][512];
    int b = blockIdx.x, t = threadIdx.x;
    int v = (t < NCHUNK) ? hist[t * NBUCK + b] : 0;
    buf[0][t] = v;
    __syncthreads();
    int src = 0;
    for (int d = 1; d < 512; d <<= 1) {
        int nv = buf[src][t] + ((t >= d) ? buf[src][t - d] : 0);
        buf[src ^ 1][t] = nv;
        src ^= 1;
        __syncthreads();
    }
    if (t < NCHUNK) baseT[b * NCHUNK + t] = buf[src][t] - v;   // exclusive over chunks
    if (t == NCHUNK - 1) colTotal[b] = buf[src][t];
}

// C) exclusive scan of bucket totals -> b_off[392]
__global__ __launch_bounds__(512) void boff_kernel(
    const int* __restrict__ colTotal, int* __restrict__ b_off)
{
    __shared__ int buf[2][512];
    int t = threadIdx.x;
    int v = (t < NBUCK) ? colTotal[t] : 0;
    buf[0][t] = v;
    __syncthreads();
    int src = 0;
    for (int d = 1; d < 512; d <<= 1) {
        int nv = buf[src][t] + ((t >= d) ? buf[src][t - d] : 0);
        buf[src ^ 1][t] = nv;
        src ^= 1;
        __syncthreads();
    }
    if (t < NBUCK) b_off[t] = buf[src][t] - v;
    if (t == NBUCK - 1) b_off[NBUCK] = buf[src][t];            // = NE
}

// D) scatter edges into bucket-contiguous rec slots (LDS rank counters)
__global__ __launch_bounds__(256) void fillb_kernel(
    const int* __restrict__ ei, const float* __restrict__ eattr,
    const int* __restrict__ baseT, const int* __restrict__ b_off,
    float4* __restrict__ rec)
{
    __shared__ int sslot[NBUCK];
    int t = threadIdx.x, c = blockIdx.x;
    for (int b = t; b < NBUCK; b += 256)
        sslot[b] = b_off[b] + baseT[b * NCHUNK + c];
    __syncthreads();
    int base = c * CH;
    for (int i = t; i < CH; i += 256) {
        int e = base + i;
        if (e < NE) {
            int row = ei[e];
            int slot = atomicAdd(&sslot[row >> 8], 1);
            float2 ea = reinterpret_cast<const float2*>(eattr)[e];
            float4 v;
            v.x = __int_as_float(row);
            v.y = __int_as_float(ei[NE + e]);
            v.z = ea.x; v.w = ea.y;
            rec[slot] = v;
        }
    }
}

// ---- P precompute for layer 0: Pr[i]=x[i]@W1[1:9], Pc[i]=x[i]@W1[9:17] ------
__global__ __launch_bounds__(256) void prep_kernel(
    const float* __restrict__ x, const float* __restrict__ W1,
    float* __restrict__ Pr, float* __restrict__ Pc)
{
    int i = blockIdx.x * 256 + threadIdx.x;
    if (i >= NN) return;
    const float4* xi = reinterpret_cast<const float4*>(x + (size_t)i * 8);
    float4 a0 = xi[0], a1 = xi[1];
    float xv[8] = {a0.x, a0.y, a0.z, a0.w, a1.x, a1.y, a1.z, a1.w};
    float pr[16], pc[16];
#pragma unroll
    for (int q = 0; q < 16; q++) { pr[q] = 0.f; pc[q] = 0.f; }
#pragma unroll
    for (int k = 0; k < 8; k++) {
        float v = xv[k];
#pragma unroll
        for (int q = 0; q < 16; q++) {
            pr[q] += v * W1[(1 + k) * 16 + q];
            pc[q] += v * W1[(9 + k) * 16 + q];
        }
    }
    float4* po = reinterpret_cast<float4*>(Pr + (size_t)i * 16);
#pragma unroll
    for (int t = 0; t < 4; t++)
        po[t] = make_float4(pr[4 * t], pr[4 * t + 1], pr[4 * t + 2], pr[4 * t + 3]);
    float4* qo = reinterpret_cast<float4*>(Pc + (size_t)i * 16);
#pragma unroll
    for (int t = 0; t < 4; t++)
        qo[t] = make_float4(pc[4 * t], pc[4 * t + 1], pc[4 * t + 2], pc[4 * t + 3]);
}

// ============ FUSED layer kernel: edge MLP + LDS sagg + node MLP =============
// Block b owns nodes [256b, 256b+256) and the bucket-contiguous edge range
// b_off[b]..b_off[b+1]. Edges within the bucket are in ARBITRARY node order —
// wave lanes hit ~unique rows, so sagg LDS atomics are near-conflict-free
// (r14's serialization came from full node-sorting; bucket sort avoids it).
template <bool WRITE_REC, bool NEED_SUM, bool HAS_NEXT>
__global__ __launch_bounds__(256, 4) void fused_kernel(
    float4* __restrict__ rec, const int* __restrict__ b_off,
    const float* __restrict__ PrIn, const float* __restrict__ PcIn,
    const float* __restrict__ gptr,
    const float* __restrict__ eW1, const float* __restrict__ eB1,
    const float* __restrict__ eW2, const float* __restrict__ eB2,
    const float* __restrict__ x,
    const float* __restrict__ nW1, const float* __restrict__ nB1,
    const float* __restrict__ nW2, const float* __restrict__ nB2,
    const float* __restrict__ nextW1,
    float* __restrict__ PrOut, float* __restrict__ PcOut,
    float* __restrict__ xout, float* __restrict__ sums)
{
    __shared__ float sagg[256][2];
    __shared__ float redE[4][2];
    __shared__ float redN[4][8];
    int tid = threadIdx.x;
    sagg[tid][0] = 0.f; sagg[tid][1] = 0.f;
    __syncthreads();

    int n0 = blockIdx.x * 256;
    int e0 = b_off[blockIdx.x], e1 = b_off[blockIdx.x + 1];

    float gval = gptr[0];
    float gterm[16];
#pragma unroll
    for (int q = 0; q < 16; q++) gterm[q] = eB1[q] + gval * eW1[q];

    float t0 = 0.f, t1 = 0.f;
    for (int e = e0 + tid; e < e1; e += 256) {
        float4 r = rec[e];
        int row = __float_as_int(r.x);
        int col = __float_as_int(r.y);
        float ea0 = r.z, ea1 = r.w;
        const float4* pr = reinterpret_cast<const float4*>(PrIn + (size_t)row * 16);
        const float4* pc = reinterpret_cast<const float4*>(PcIn + (size_t)col * 16);
        float4 r0 = pr[0], r1 = pr[1], r2 = pr[2], r3 = pr[3];
        float4 c0 = pc[0], c1 = pc[1], c2 = pc[2], c3 = pc[3];
        float h[16];
        h[0]  = gterm[0]  + r0.x + c0.x;
        h[1]  = gterm[1]  + r0.y + c0.y;
        h[2]  = gterm[2]  + r0.z + c0.z;
        h[3]  = gterm[3]  + r0.w + c0.w;
        h[4]  = gterm[4]  + r1.x + c1.x;
        h[5]  = gterm[5]  + r1.y + c1.y;
        h[6]  = gterm[6]  + r1.z + c1.z;
        h[7]  = gterm[7]  + r1.w + c1.w;
        h[8]  = gterm[8]  + r2.x + c2.x;
        h[9]  = gterm[9]  + r2.y + c2.y;
        h[10] = gterm[10] + r2.z + c2.z;
        h[11] = gterm[11] + r2.w + c2.w;
        h[12] = gterm[12] + r3.x + c3.x;
        h[13] = gterm[13] + r3.y + c3.y;
        h[14] = gterm[14] + r3.z + c3.z;
        h[15] = gterm[15] + r3.w + c3.w;
#pragma unroll
        for (int q = 0; q < 16; q++) {
            h[q] += ea0 * eW1[17 * 16 + q];
            h[q] += ea1 * eW1[18 * 16 + q];
        }
        float s0 = eB2[0], s1 = eB2[1];
#pragma unroll
        for (int q = 0; q < 16; q++) {
            float rr = fmaxf(h[q], 0.f);
            s0 += rr * eW2[2 * q];
            s1 += rr * eW2[2 * q + 1];
        }
        if (WRITE_REC) {
            float4 w;
            w.x = r.x; w.y = r.y; w.z = s0; w.w = s1;
            rec[e] = w;
        }
        int li = row - n0;
        atomicAdd(&sagg[li][0], s0);
        atomicAdd(&sagg[li][1], s1);
        t0 += s0; t1 += s1;
    }

    if (NEED_SUM) {
        float r0 = wave_red(t0);
        float r1 = wave_red(t1);
        int wave = tid >> 6, lane = tid & 63;
        if (lane == 0) { redE[wave][0] = r0; redE[wave][1] = r1; }
    }
    __syncthreads();   // sagg complete (and redE visible)
    if (NEED_SUM && tid == 0) {
        atomicAdd(&sums[0], redE[0][0] + redE[1][0] + redE[2][0] + redE[3][0]);
        atomicAdd(&sums[1], redE[0][1] + redE[1][1] + redE[2][1] + redE[3][1]);
    }

    // ---------------- phase 2: node MLP ----------------
    int n = n0 + tid;
    float out[8];
#pragma unroll
    for (int m = 0; m < 8; m++) out[m] = 0.f;

    if (n < NN) {
        float in[11];
        in[0] = gval;
        const float4* xi = reinterpret_cast<const float4*>(x + (size_t)n * 8);
        float4 a0 = xi[0], a1 = xi[1];
        in[1] = a0.x; in[2] = a0.y; in[3] = a0.z; in[4] = a0.w;
        in[5] = a1.x; in[6] = a1.y; in[7] = a1.z; in[8] = a1.w;
        in[9] = sagg[tid][0]; in[10] = sagg[tid][1];

        float h[16];
#pragma unroll
        for (int q = 0; q < 16; q++) h[q] = nB1[q];
#pragma unroll
        for (int k = 0; k < 11; k++) {
            float v = in[k];
#pragma unroll
            for (int q = 0; q < 16; q++) h[q] += v * nW1[k * 16 + q];
        }
#pragma unroll
        for (int m = 0; m < 8; m++) out[m] = nB2[m];
#pragma unroll
        for (int q = 0; q < 16; q++) {
            float hq = fmaxf(h[q], 0.f);
#pragma unroll
            for (int m = 0; m < 8; m++) out[m] += hq * nW2[q * 8 + m];
        }
        float4* xo = reinterpret_cast<float4*>(xout + (size_t)n * 8);
        xo[0] = make_float4(out[0], out[1], out[2], out[3]);
        xo[1] = make_float4(out[4], out[5], out[6], out[7]);

        if (HAS_NEXT) {
            float pr[16], pc[16];
#pragma unroll
            for (int q = 0; q < 16; q++) { pr[q] = 0.f; pc[q] = 0.f; }
#pragma unroll
            for (int k = 0; k < 8; k++) {
                float v = out[k];
#pragma unroll
                for (int q = 0; q < 16; q++) {
                    pr[q] += v * nextW1[(1 + k) * 16 + q];
                    pc[q] += v * nextW1[(9 + k) * 16 + q];
                }
            }
            float4* po = reinterpret_cast<float4*>(PrOut + (size_t)n * 16);
#pragma unroll
            for (int t = 0; t < 4; t++)
                po[t] = make_float4(pr[4*t], pr[4*t+1], pr[4*t+2], pr[4*t+3]);
            float4* qo = reinterpret_cast<float4*>(PcOut + (size_t)n * 16);
#pragma unroll
            for (int t = 0; t < 4; t++)
                qo[t] = make_float4(pc[4*t], pc[4*t+1], pc[4*t+2], pc[4*t+3]);
        }
    }
    if (NEED_SUM) {
        float r[8];
#pragma unroll
        for (int m = 0; m < 8; m++) r[m] = wave_red(out[m]);
        int wave = tid >> 6, lane = tid & 63;
        if (lane == 0) {
#pragma unroll
            for (int m = 0; m < 8; m++) redN[wave][m] = r[m];
        }
        __syncthreads();
        if (tid == 0) {
#pragma unroll
            for (int m = 0; m < 8; m++) {
                float s = redN[0][m] + redN[1][m] + redN[2][m] + redN[3][m];
                atomicAdd(&sums[2 + m], s);
            }
        }
    }
}

// ---------------- global block: MLP(11->16->1), single thread ----------------
__global__ void glob_kernel(const float* __restrict__ sums,
                            const float* __restrict__ gold,
                            const float* __restrict__ W1, const float* __restrict__ B1,
                            const float* __restrict__ W2, const float* __restrict__ B2,
                            float* __restrict__ gnew)
{
    if (threadIdx.x == 0 && blockIdx.x == 0) {
        float in[11];
#pragma unroll
        for (int j = 0; j < 8; j++) in[j] = sums[2 + j] * (1.0f / NN);
        in[8] = sums[0] * (1.0f / NE);
        in[9] = sums[1] * (1.0f / NE);
        in[10] = gold[0];
        float acc = B2[0];
#pragma unroll
        for (int j = 0; j < 16; j++) {
            float h = B1[j];
#pragma unroll
            for (int k = 0; k < 11; k++) h += in[k] * W1[k * 16 + j];
            acc += fmaxf(h, 0.f) * W2[j];
        }
        gnew[0] = acc;
    }
}

extern "C" void kernel_launch(void* const* d_in, const int* in_sizes, int n_in,
                              void* d_out, int out_size, void* d_ws, size_t ws_size,
                              hipStream_t stream) {
    const float* x     = (const float*)d_in[0];
    const int*   ei    = (const int*)d_in[1];
    const float* eattr = (const float*)d_in[2];
    const float* g     = (const float*)d_in[3];
    const float* eW1 = (const float*)d_in[4];
    const float* eB1 = (const float*)d_in[5];
    const float* eW2 = (const float*)d_in[6];
    const float* eB2 = (const float*)d_in[7];
    const float* nW1 = (const float*)d_in[8];
    const float* nB1 = (const float*)d_in[9];
    const float* nW2 = (const float*)d_in[10];
    const float* nB2 = (const float*)d_in[11];
    const float* gW1 = (const float*)d_in[12];
    const float* gB1 = (const float*)d_in[13];
    const float* gW2 = (const float*)d_in[14];
    const float* gB2 = (const float*)d_in[15];
    float* out = (float*)d_out;

    char* ws = (char*)d_ws;
    float*  xb0    = (float*)(ws);                 // 3,200,000
    int*    b_off  = (int*)  (ws + 3200000);       // 392*4 -> pad 1,600
    float*  sums   = (float*)(ws + 3201600);       // 2 slabs x 16 + g1/g2 (192 B)
    float*  g1     = (float*)(ws + 3201728);
    float*  g2     = g1 + 1;
    float4* rec    = (float4*)(ws + 3201792);      // 25,600,000 -> 28,801,792
    float*  PrA    = (float*)(ws + 28801792);      // 6,400,000 -> 35,201,792
    float*  PcA    = (float*)(ws + 35201792);      // 6,400,000 -> 41,601,792
    float*  PrB    = (float*)(ws + 41601792);      // 6,400,000 -> 48,001,792
    float*  PcB    = (float*)(ws + 48001792);      // 6,400,000 -> 54,401,792
    // build-phase temporaries alias PrB (dead until fused L0 phase 2):
    int*    hist     = (int*)PrB;                  // 391*391*4 = 611,524
    int*    baseT    = (int*)((char*)PrB + 611584);// 611,524
    int*    colTotal = (int*)((char*)PrB + 1223168);// 1,564

    dim3 blk(256);
    dim3 cgrid(NCHUNK);                            // 391 chunks
    dim3 bgrid(NBUCK);                             // 391 buckets
    dim3 ngrid((NN + 255) / 256);                  // 391

    // ---- bucket-sort build (no global atomics) ----
    hipMemsetAsync(sums, 0, 192, stream);
    hist_kernel<<<cgrid, blk, 0, stream>>>(ei, hist);
    bscan_kernel<<<bgrid, 512, 0, stream>>>(hist, baseT, colTotal);
    boff_kernel<<<1, 512, 0, stream>>>(colTotal, b_off);
    fillb_kernel<<<cgrid, blk, 0, stream>>>(ei, eattr, baseT, b_off, rec);
    prep_kernel<<<ngrid, blk, 0, stream>>>(x, eW1, PrA, PcA);

    // ---- layer 0: P=A -> writes P=B; rec.zw: ea -> L0 edge emb; x -> xb0 ----
    fused_kernel<true, true, true><<<bgrid, blk, 0, stream>>>(
        rec, b_off, PrA, PcA, g,
        eW1, eB1, eW2, eB2,
        x, nW1, nB1, nW2, nB2,
        eW1 + 304, PrB, PcB, xb0, sums);
    glob_kernel<<<1, 64, 0, stream>>>(sums, g, gW1, gB1, gW2, gB2, g1);

    // ---- layer 1: P=B -> writes P=A; rec.zw: L0 -> L1 emb; xb0 -> d_out ----
    fused_kernel<true, true, true><<<bgrid, blk, 0, stream>>>(
        rec, b_off, PrB, PcB, g1,
        eW1 + 304, eB1 + 16, eW2 + 32, eB2 + 2,
        xb0, nW1 + 176, nB1 + 16, nW2 + 128, nB2 + 8,
        eW1 + 608, PrA, PcA, (float*)out, sums + 16);
    glob_kernel<<<1, 64, 0, stream>>>(sums + 16, g1, gW1 + 176, gB1 + 16, gW2 + 16, gB2 + 1, g2);

    // ---- layer 2: P=A; no rec rewrite, no P out; d_out -> d_out ----
    fused_kernel<false, false, false><<<bgrid, blk, 0, stream>>>(
        rec, b_off, PrA, PcA, g2,
        eW1 + 608, eB1 + 32, eW2 + 64, eB2 + 4,
        (float*)out, nW1 + 352, nB1 + 32, nW2 + 256, nB2 + 16,
        nullptr, nullptr, nullptr, out, sums);
}

// Round 17
// 346.901 us; speedup vs baseline: 1.2985x; 1.0676x over previous
//
#include <hip/hip_runtime.h>

#define NN 100000
#define NE 1600000
#define CH 4096                                  // edges per chunk
#define NCHUNK ((NE + CH - 1) / CH)              // 391
#define NBUCK ((NN + 255) / 256)                 // 391 (256-node buckets = fused blocks)

__device__ __forceinline__ float wave_red(float v) {
#pragma unroll
    for (int off = 32; off > 0; off >>= 1) v += __shfl_down(v, off, 64);
    return v;
}

// ---------------- build phase: bucket sort, zero global atomics --------------
__global__ __launch_bounds__(256) void hist_kernel(
    const int* __restrict__ ei, int* __restrict__ hist)
{
    __shared__ int h[NBUCK];
    int t = threadIdx.x, c = blockIdx.x;
    for (int b = t; b < NBUCK; b += 256) h[b] = 0;
    __syncthreads();
    int base = c * CH;
    for (int i = t; i < CH; i += 256) {
        int e = base + i;
        if (e < NE) atomicAdd(&h[ei[e] >> 8], 1);
    }
    __syncthreads();
    for (int b = t; b < NBUCK; b += 256) hist[c * NBUCK + b] = h[b];
}

__global__ __launch_bounds__(512) void bscan_kernel(
    const int* __restrict__ hist, int* __restrict__ baseT, int* __restrict__ colTotal)
{
    __shared__ int buf[2][512];
    int b = blockIdx.x, t = threadIdx.x;
    int v = (t < NCHUNK) ? hist[t * NBUCK + b] : 0;
    buf[0][t] = v;
    __syncthreads();
    int src = 0;
    for (int d = 1; d < 512; d <<= 1) {
        int nv = buf[src][t] + ((t >= d) ? buf[src][t - d] : 0);
        buf[src ^ 1][t] = nv;
        src ^= 1;
        __syncthreads();
    }
    if (t < NCHUNK) baseT[b * NCHUNK + t] = buf[src][t] - v;   // exclusive over chunks
    if (t == NCHUNK - 1) colTotal[b] = buf[src][t];
}

__global__ __launch_bounds__(512) void boff_kernel(
    const int* __restrict__ colTotal, int* __restrict__ b_off)
{
    __shared__ int buf[2][512];
    int t = threadIdx.x;
    int v = (t < NBUCK) ? colTotal[t] : 0;
    buf[0][t] = v;
    __syncthreads();
    int src = 0;
    for (int d = 1; d < 512; d <<= 1) {
        int nv = buf[src][t] + ((t >= d) ? buf[src][t - d] : 0);
        buf[src ^ 1][t] = nv;
        src ^= 1;
        __syncthreads();
    }
    if (t < NBUCK) b_off[t] = buf[src][t] - v;
    if (t == NBUCK - 1) b_off[NBUCK] = buf[src][t];            // = NE
}

__global__ __launch_bounds__(256) void fillb_kernel(
    const int* __restrict__ ei, const float* __restrict__ eattr,
    const int* __restrict__ baseT, const int* __restrict__ b_off,
    float4* __restrict__ rec)
{
    __shared__ int sslot[NBUCK];
    int t = threadIdx.x, c = blockIdx.x;
    for (int b = t; b < NBUCK; b += 256)
        sslot[b] = b_off[b] + baseT[b * NCHUNK + c];
    __syncthreads();
    int base = c * CH;
    for (int i = t; i < CH; i += 256) {
        int e = base + i;
        if (e < NE) {
            int row = ei[e];
            int slot = atomicAdd(&sslot[row >> 8], 1);
            float2 ea = reinterpret_cast<const float2*>(eattr)[e];
            float4 v;
            v.x = __int_as_float(row);
            v.y = __int_as_float(ei[NE + e]);
            v.z = ea.x; v.w = ea.y;
            rec[slot] = v;
        }
    }
}

// ---- P precompute for layer 0: Pr[i]=x[i]@W1[1:9], Pc[i]=x[i]@W1[9:17] ------
__global__ __launch_bounds__(256) void prep_kernel(
    const float* __restrict__ x, const float* __restrict__ W1,
    float* __restrict__ Pr, float* __restrict__ Pc)
{
    int i = blockIdx.x * 256 + threadIdx.x;
    if (i >= NN) return;
    const float4* xi = reinterpret_cast<const float4*>(x + (size_t)i * 8);
    float4 a0 = xi[0], a1 = xi[1];
    float xv[8] = {a0.x, a0.y, a0.z, a0.w, a1.x, a1.y, a1.z, a1.w};
    float pr[16], pc[16];
#pragma unroll
    for (int q = 0; q < 16; q++) { pr[q] = 0.f; pc[q] = 0.f; }
#pragma unroll
    for (int k = 0; k < 8; k++) {
        float v = xv[k];
#pragma unroll
        for (int q = 0; q < 16; q++) {
            pr[q] += v * W1[(1 + k) * 16 + q];
            pc[q] += v * W1[(9 + k) * 16 + q];
        }
    }
    float4* po = reinterpret_cast<float4*>(Pr + (size_t)i * 16);
#pragma unroll
    for (int t = 0; t < 4; t++)
        po[t] = make_float4(pr[4 * t], pr[4 * t + 1], pr[4 * t + 2], pr[4 * t + 3]);
    float4* qo = reinterpret_cast<float4*>(Pc + (size_t)i * 16);
#pragma unroll
    for (int t = 0; t < 4; t++)
        qo[t] = make_float4(pc[4 * t], pc[4 * t + 1], pc[4 * t + 2], pc[4 * t + 3]);
}

// ============ FUSED layer kernel: edge MLP + LDS Pr window + node MLP ========
// Block b owns nodes [256b, 256b+256) and bucket-contiguous edges.
// Pr for the block's 256 rows is staged in LDS TRANSPOSED (sPrT[j*256+li]):
// per-edge reads hit bank li%32 — random li => ~2 lanes/bank => conflict-free
// (m136). This removes 1.6M random global Pr line-requests per layer, which
// r16's bucket-random order exposed (r15 row-sorted had wave-broadcast Pr).
template <bool WRITE_REC, bool NEED_SUM, bool HAS_NEXT>
__global__ __launch_bounds__(256, 4) void fused_kernel(
    float4* __restrict__ rec, const int* __restrict__ b_off,
    const float* __restrict__ PrIn, const float* __restrict__ PcIn,
    const float* __restrict__ gptr,
    const float* __restrict__ eW1, const float* __restrict__ eB1,
    const float* __restrict__ eW2, const float* __restrict__ eB2,
    const float* __restrict__ x,
    const float* __restrict__ nW1, const float* __restrict__ nB1,
    const float* __restrict__ nW2, const float* __restrict__ nB2,
    const float* __restrict__ nextW1,
    float* __restrict__ PrOut, float* __restrict__ PcOut,
    float* __restrict__ xout, float* __restrict__ sums)
{
    __shared__ float sPrT[16 * 256];             // 16 KB, transposed
    __shared__ float sagg[256][2];
    __shared__ float redE[4][2];
    __shared__ float redN[4][8];
    int tid = threadIdx.x;
    sagg[tid][0] = 0.f; sagg[tid][1] = 0.f;

    int n0 = blockIdx.x * 256;
    int nrow = n0 + tid;
    if (nrow < NN) {
        const float4* ps = reinterpret_cast<const float4*>(PrIn + (size_t)nrow * 16);
        float4 p0 = ps[0], p1 = ps[1], p2 = ps[2], p3 = ps[3];
        sPrT[0 * 256 + tid]  = p0.x; sPrT[1 * 256 + tid]  = p0.y;
        sPrT[2 * 256 + tid]  = p0.z; sPrT[3 * 256 + tid]  = p0.w;
        sPrT[4 * 256 + tid]  = p1.x; sPrT[5 * 256 + tid]  = p1.y;
        sPrT[6 * 256 + tid]  = p1.z; sPrT[7 * 256 + tid]  = p1.w;
        sPrT[8 * 256 + tid]  = p2.x; sPrT[9 * 256 + tid]  = p2.y;
        sPrT[10 * 256 + tid] = p2.z; sPrT[11 * 256 + tid] = p2.w;
        sPrT[12 * 256 + tid] = p3.x; sPrT[13 * 256 + tid] = p3.y;
        sPrT[14 * 256 + tid] = p3.z; sPrT[15 * 256 + tid] = p3.w;
    }
    __syncthreads();

    int e0 = b_off[blockIdx.x], e1 = b_off[blockIdx.x + 1];

    float gval = gptr[0];
    float gterm[16];
#pragma unroll
    for (int q = 0; q < 16; q++) gterm[q] = eB1[q] + gval * eW1[q];

    float t0 = 0.f, t1 = 0.f;
    for (int e = e0 + tid; e < e1; e += 256) {
        float4 r = rec[e];
        int row = __float_as_int(r.x);
        int col = __float_as_int(r.y);
        float ea0 = r.z, ea1 = r.w;
        int li = row - n0;
        const float4* pc = reinterpret_cast<const float4*>(PcIn + (size_t)col * 16);
        float4 c0 = pc[0], c1 = pc[1], c2 = pc[2], c3 = pc[3];
        float h[16];
#pragma unroll
        for (int q = 0; q < 16; q++) h[q] = gterm[q] + sPrT[q * 256 + li];
        h[0]  += c0.x; h[1]  += c0.y; h[2]  += c0.z; h[3]  += c0.w;
        h[4]  += c1.x; h[5]  += c1.y; h[6]  += c1.z; h[7]  += c1.w;
        h[8]  += c2.x; h[9]  += c2.y; h[10] += c2.z; h[11] += c2.w;
        h[12] += c3.x; h[13] += c3.y; h[14] += c3.z; h[15] += c3.w;
#pragma unroll
        for (int q = 0; q < 16; q++) {
            h[q] += ea0 * eW1[17 * 16 + q];
            h[q] += ea1 * eW1[18 * 16 + q];
        }
        float s0 = eB2[0], s1 = eB2[1];
#pragma unroll
        for (int q = 0; q < 16; q++) {
            float rr = fmaxf(h[q], 0.f);
            s0 += rr * eW2[2 * q];
            s1 += rr * eW2[2 * q + 1];
        }
        if (WRITE_REC) {
            float4 w;
            w.x = r.x; w.y = r.y; w.z = s0; w.w = s1;
            rec[e] = w;
        }
        atomicAdd(&sagg[li][0], s0);
        atomicAdd(&sagg[li][1], s1);
        t0 += s0; t1 += s1;
    }

    if (NEED_SUM) {
        float r0 = wave_red(t0);
        float r1 = wave_red(t1);
        int wave = tid >> 6, lane = tid & 63;
        if (lane == 0) { redE[wave][0] = r0; redE[wave][1] = r1; }
    }
    __syncthreads();   // sagg complete (and redE visible)
    if (NEED_SUM && tid == 0) {
        atomicAdd(&sums[0], redE[0][0] + redE[1][0] + redE[2][0] + redE[3][0]);
        atomicAdd(&sums[1], redE[0][1] + redE[1][1] + redE[2][1] + redE[3][1]);
    }

    // ---------------- phase 2: node MLP ----------------
    int n = n0 + tid;
    float out[8];
#pragma unroll
    for (int m = 0; m < 8; m++) out[m] = 0.f;

    if (n < NN) {
        float in[11];
        in[0] = gval;
        const float4* xi = reinterpret_cast<const float4*>(x + (size_t)n * 8);
        float4 a0 = xi[0], a1 = xi[1];
        in[1] = a0.x; in[2] = a0.y; in[3] = a0.z; in[4] = a0.w;
        in[5] = a1.x; in[6] = a1.y; in[7] = a1.z; in[8] = a1.w;
        in[9] = sagg[tid][0]; in[10] = sagg[tid][1];

        float h[16];
#pragma unroll
        for (int q = 0; q < 16; q++) h[q] = nB1[q];
#pragma unroll
        for (int k = 0; k < 11; k++) {
            float v = in[k];
#pragma unroll
            for (int q = 0; q < 16; q++) h[q] += v * nW1[k * 16 + q];
        }
#pragma unroll
        for (int m = 0; m < 8; m++) out[m] = nB2[m];
#pragma unroll
        for (int q = 0; q < 16; q++) {
            float hq = fmaxf(h[q], 0.f);
#pragma unroll
            for (int m = 0; m < 8; m++) out[m] += hq * nW2[q * 8 + m];
        }
        float4* xo = reinterpret_cast<float4*>(xout + (size_t)n * 8);
        xo[0] = make_float4(out[0], out[1], out[2], out[3]);
        xo[1] = make_float4(out[4], out[5], out[6], out[7]);

        if (HAS_NEXT) {
            float pr[16], pc[16];
#pragma unroll
            for (int q = 0; q < 16; q++) { pr[q] = 0.f; pc[q] = 0.f; }
#pragma unroll
            for (int k = 0; k < 8; k++) {
                float v = out[k];
#pragma unroll
                for (int q = 0; q < 16; q++) {
                    pr[q] += v * nextW1[(1 + k) * 16 + q];
                    pc[q] += v * nextW1[(9 + k) * 16 + q];
                }
            }
            float4* po = reinterpret_cast<float4*>(PrOut + (size_t)n * 16);
#pragma unroll
            for (int t = 0; t < 4; t++)
                po[t] = make_float4(pr[4*t], pr[4*t+1], pr[4*t+2], pr[4*t+3]);
            float4* qo = reinterpret_cast<float4*>(PcOut + (size_t)n * 16);
#pragma unroll
            for (int t = 0; t < 4; t++)
                qo[t] = make_float4(pc[4*t], pc[4*t+1], pc[4*t+2], pc[4*t+3]);
        }
    }
    if (NEED_SUM) {
        float r[8];
#pragma unroll
        for (int m = 0; m < 8; m++) r[m] = wave_red(out[m]);
        int wave = tid >> 6, lane = tid & 63;
        if (lane == 0) {
#pragma unroll
            for (int m = 0; m < 8; m++) redN[wave][m] = r[m];
        }
        __syncthreads();
        if (tid == 0) {
#pragma unroll
            for (int m = 0; m < 8; m++) {
                float s = redN[0][m] + redN[1][m] + redN[2][m] + redN[3][m];
                atomicAdd(&sums[2 + m], s);
            }
        }
    }
}

// ---------------- global block: MLP(11->16->1), single thread ----------------
__global__ void glob_kernel(const float* __restrict__ sums,
                            const float* __restrict__ gold,
                            const float* __restrict__ W1, const float* __restrict__ B1,
                            const float* __restrict__ W2, const float* __restrict__ B2,
                            float* __restrict__ gnew)
{
    if (threadIdx.x == 0 && blockIdx.x == 0) {
        float in[11];
#pragma unroll
        for (int j = 0; j < 8; j++) in[j] = sums[2 + j] * (1.0f / NN);
        in[8] = sums[0] * (1.0f / NE);
        in[9] = sums[1] * (1.0f / NE);
        in[10] = gold[0];
        float acc = B2[0];
#pragma unroll
        for (int j = 0; j < 16; j++) {
            float h = B1[j];
#pragma unroll
            for (int k = 0; k < 11; k++) h += in[k] * W1[k * 16 + j];
            acc += fmaxf(h, 0.f) * W2[j];
        }
        gnew[0] = acc;
    }
}

extern "C" void kernel_launch(void* const* d_in, const int* in_sizes, int n_in,
                              void* d_out, int out_size, void* d_ws, size_t ws_size,
                              hipStream_t stream) {
    const float* x     = (const float*)d_in[0];
    const int*   ei    = (const int*)d_in[1];
    const float* eattr = (const float*)d_in[2];
    const float* g     = (const float*)d_in[3];
    const float* eW1 = (const float*)d_in[4];
    const float* eB1 = (const float*)d_in[5];
    const float* eW2 = (const float*)d_in[6];
    const float* eB2 = (const float*)d_in[7];
    const float* nW1 = (const float*)d_in[8];
    const float* nB1 = (const float*)d_in[9];
    const float* nW2 = (const float*)d_in[10];
    const float* nB2 = (const float*)d_in[11];
    const float* gW1 = (const float*)d_in[12];
    const float* gB1 = (const float*)d_in[13];
    const float* gW2 = (const float*)d_in[14];
    const float* gB2 = (const float*)d_in[15];
    float* out = (float*)d_out;

    char* ws = (char*)d_ws;
    float*  xb0    = (float*)(ws);                 // 3,200,000
    int*    b_off  = (int*)  (ws + 3200000);       // 392*4 -> pad 1,600
    float*  sums   = (float*)(ws + 3201600);       // 2 slabs x 16 + g1/g2 (192 B)
    float*  g1     = (float*)(ws + 3201728);
    float*  g2     = g1 + 1;
    float4* rec    = (float4*)(ws + 3201792);      // 25,600,000 -> 28,801,792
    float*  PrA    = (float*)(ws + 28801792);      // 6,400,000 -> 35,201,792
    float*  PcA    = (float*)(ws + 35201792);      // 6,400,000 -> 41,601,792
    float*  PrB    = (float*)(ws + 41601792);      // 6,400,000 -> 48,001,792
    float*  PcB    = (float*)(ws + 48001792);      // 6,400,000 -> 54,401,792
    // build-phase temporaries alias PrB (dead until fused L0 phase 2):
    int*    hist     = (int*)PrB;                  // 391*391*4 = 611,524
    int*    baseT    = (int*)((char*)PrB + 611584);// 611,524
    int*    colTotal = (int*)((char*)PrB + 1223168);// 1,564

    dim3 blk(256);
    dim3 cgrid(NCHUNK);                            // 391 chunks
    dim3 bgrid(NBUCK);                             // 391 buckets
    dim3 ngrid((NN + 255) / 256);                  // 391

    // ---- bucket-sort build (no global atomics) ----
    hipMemsetAsync(sums, 0, 192, stream);
    hist_kernel<<<cgrid, blk, 0, stream>>>(ei, hist);
    bscan_kernel<<<bgrid, 512, 0, stream>>>(hist, baseT, colTotal);
    boff_kernel<<<1, 512, 0, stream>>>(colTotal, b_off);
    fillb_kernel<<<cgrid, blk, 0, stream>>>(ei, eattr, baseT, b_off, rec);
    prep_kernel<<<ngrid, blk, 0, stream>>>(x, eW1, PrA, PcA);

    // ---- layer 0: P=A -> writes P=B; rec.zw: ea -> L0 edge emb; x -> xb0 ----
    fused_kernel<true, true, true><<<bgrid, blk, 0, stream>>>(
        rec, b_off, PrA, PcA, g,
        eW1, eB1, eW2, eB2,
        x, nW1, nB1, nW2, nB2,
        eW1 + 304, PrB, PcB, xb0, sums);
    glob_kernel<<<1, 64, 0, stream>>>(sums, g, gW1, gB1, gW2, gB2, g1);

    // ---- layer 1: P=B -> writes P=A; rec.zw: L0 -> L1 emb; xb0 -> d_out ----
    fused_kernel<true, true, true><<<bgrid, blk, 0, stream>>>(
        rec, b_off, PrB, PcB, g1,
        eW1 + 304, eB1 + 16, eW2 + 32, eB2 + 2,
        xb0, nW1 + 176, nB1 + 16, nW2 + 128, nB2 + 8,
        eW1 + 608, PrA, PcA, (float*)out, sums + 16);
    glob_kernel<<<1, 64, 0, stream>>>(sums + 16, g1, gW1 + 176, gB1 + 16, gW2 + 16, gB2 + 1, g2);

    // ---- layer 2: P=A; no rec rewrite, no P out; d_out -> d_out ----
    fused_kernel<false, false, false><<<bgrid, blk, 0, stream>>>(
        rec, b_off, PrA, PcA, g2,
        eW1 + 608, eB1 + 32, eW2 + 64, eB2 + 4,
        (float*)out, nW1 + 352, nB1 + 32, nW2 + 256, nB2 + 16,
        nullptr, nullptr, nullptr, out, sums);
}